// Round 1
// 410.320 us; speedup vs baseline: 1.0094x; 1.0094x over previous
//
#include <hip/hip_runtime.h>

#define Bsz 4096
#define Tt  256
#define Ff  32
#define H1  64
#define H2  32
#define NTAPS 3
#define BT  8       // 512 blocks -> 2 co-resident blocks/CU
#define NTHR 512    // 8 waves: 0-3 = L1 path, 4-7 = L2 path + x-DMA -> 4 waves/SIMD
#define CH  16      // x-staging chunk (timesteps)

typedef _Float16 half8  __attribute__((ext_vector_type(8)));
typedef __fp16   fp16x2 __attribute__((ext_vector_type(2)));   // cvt_pkrtz return type
typedef float    f32x4  __attribute__((ext_vector_type(4)));

#define H1S 72   // f16 row strides (16B-aligned, bank-spread)
#define H2S 40
#define HDS 33

// fused LSTM unit: 5 exp + 3 rcp
__device__ __forceinline__ float lstm_unit(float pi, float pf, float pg, float po,
                                           float& c) {
    const float K1 = 1.4426950408889634f;   // log2(e)
    float ei = __builtin_amdgcn_exp2f(-K1 * pi);
    float ef = __builtin_amdgcn_exp2f(-K1 * pf);
    float eg = __builtin_amdgcn_exp2f(-2.0f * K1 * __builtin_fabsf(pg));
    float eo = __builtin_amdgcn_exp2f(-K1 * po);
    float f_ = __builtin_amdgcn_rcpf(1.0f + ef);
    float ig = (1.0f - eg) * __builtin_amdgcn_rcpf((1.0f + ei) * (1.0f + eg));
    ig = __builtin_copysignf(ig, pg);
    c = f_ * c + ig;
    float ec = __builtin_amdgcn_exp2f(-2.0f * K1 * __builtin_fabsf(c));
    float th = (1.0f - ec) * __builtin_amdgcn_rcpf((1.0f + eo) * (1.0f + ec));
    return __builtin_copysignf(th, c);
}

#define MFMA16(a, b, c) __builtin_amdgcn_mfma_f32_16x16x32_f16((a), (b), (c), 0, 0, 0)

// async global->LDS DMA, 16B per lane; LDS dst = uniform base + lane*16
__device__ __forceinline__ void dma16(const float* gp, const float* lp) {
    __builtin_amdgcn_global_load_lds(
        (const __attribute__((address_space(1))) void*)gp,
        (__attribute__((address_space(3))) void*)lp, 16, 0, 0);
}

__global__ __launch_bounds__(NTHR, 4)
void lstm2_fused(const float* __restrict__ x,
                 const float* __restrict__ Wih1, const float* __restrict__ Whh1,
                 const float* __restrict__ bih1, const float* __restrict__ bhh1,
                 const float* __restrict__ Wih2, const float* __restrict__ Whh2,
                 const float* __restrict__ bih2, const float* __restrict__ bhh2,
                 const float* __restrict__ Whead, const float* __restrict__ bhead,
                 float* __restrict__ out)
{
    __shared__ __align__(16) _Float16 sH1[2][BT][H1S];
    __shared__ __align__(16) _Float16 sH2[2][BT][H2S];
    // x chunk: [buf][t][f4][b][4] f32 — (f4-major, b-minor) so DMA lane*16B is contiguous
    __shared__ __align__(16) float    sXC[2][CH][8][8][4];
    __shared__ __align__(16) float    sHead[BT][HDS];

    const int tid  = threadIdx.x;
    const int wid  = tid >> 6;        // 0..7
    const int lane = tid & 63;
    const int l15  = lane & 15;
    const int q    = lane >> 4;       // 0..3
    const int row8 = l15 & 7;         // A-frag rows duplicate with period 8
    const int b0   = blockIdx.x * BT;
    const int w4   = wid & 3;
    const bool isL1 = (wid < 4);      // waves 0-3: L1; waves 4-7: L2 + DMA

    // L1: wave owns h-tile `w4`
    const int colL1 = w4 * 16 + l15;
    const int r0  = (q >> 1) * 2, r1 = r0 + 1;
    const int bLo = (q & 1) * 4 + (q >> 1) * 2;
    // L2: wave-pair duplicates h-tile hT; wpar splits batches
    const int hT   = w4 >> 1, wpar = w4 & 1;
    const int hL2  = hT * 16 + l15;
    const int rL2  = 2 * wpar + (q >> 1);
    const int bL2  = (q & 1) * 4 + 2 * wpar + (q >> 1);

    // per-lane DMA source base: batch bL, float-quad f4L
    const int bL  = lane & 7;
    const int f4L = lane >> 3;
    const float* gbase = x + (size_t)(b0 + bL) * Tt * Ff + f4L * 4;

    // ---- prologue: L2-waves kick chunk 0 DMA immediately ----
    if (!isL1) {
        #pragma unroll
        for (int j = 0; j < 4; ++j) {
            int t = (w4 << 2) | j;
            dma16(gbase + (size_t)t * Ff, &sXC[0][t][0][0][0]);
        }
    }

    // ---- weight fragments (registers, one time) — HALF the weights per wave ----
    half8 w[4][3];
    float bias[4];
    if (isL1) {
        #pragma unroll
        for (int G = 0; G < 4; ++G) {
            int gr = G * 64 + w4 * 16 + l15;          // L1 gate row
            #pragma unroll
            for (int c = 0; c < 3; ++c) {
                half8 v;
                #pragma unroll
                for (int e = 0; e < 8; ++e) {
                    int k = c * 32 + q * 8 + e;       // K: 0..63 h1(t-1), 64..95 x(t)
                    float f = (k < H1) ? Whh1[gr * H1 + k] : Wih1[gr * Ff + (k - H1)];
                    v[e] = (_Float16)f;
                }
                w[G][c] = v;
            }
            bias[G] = bih1[gr] + bhh1[gr];
        }
    } else {
        #pragma unroll
        for (int G = 0; G < 4; ++G) {
            int gr = G * 32 + hT * 16 + l15;          // L2 gate row
            #pragma unroll
            for (int c = 0; c < 3; ++c) {
                half8 v;
                #pragma unroll
                for (int e = 0; e < 8; ++e) {
                    int kk = q * 8 + e;               // K: c0 h2(t-1), c1/c2 h1(t)
                    float f = (c == 0) ? Whh2[gr * H2 + kk]
                                       : Wih2[gr * H1 + (c - 1) * 32 + kk];
                    v[e] = (_Float16)f;
                }
                w[G][c] = v;
            }
            bias[G] = bih2[gr] + bhh2[gr];
        }
    }

    // ---- zero h(-1) buffers ----
    for (int idx = tid; idx < BT * H1S; idx += NTHR) ((_Float16*)sH1[1])[idx] = (_Float16)0.0f;
    for (int idx = tid; idx < BT * H2S; idx += NTHR) ((_Float16*)sH2[1])[idx] = (_Float16)0.0f;

    __syncthreads();   // drains chunk-0 DMA (vmcnt) + init writes

    float csA = 0.0f, csB = 0.0f;   // L1 waves: 2 cell states; L2 waves: csA only

    for (int i = 0; i <= Tt; ++i) {
        const int cur = i & 1, nxt = cur ^ 1;
        const int t16 = i & (CH - 1), cbuf = (i >> 4) & 1;

        // ---- DMA issue at TOP of boundary step: latency hides under this step's
        //      compute before the barrier's vmcnt drain ----
        if (!isL1 && t16 == 0 && i + CH < Tt) {
            const float* gb = gbase + (size_t)(i + CH) * Ff;
            #pragma unroll
            for (int j = 0; j < 4; ++j) {
                int t = (w4 << 2) | j;
                dma16(gb + (size_t)t * Ff, &sXC[cbuf ^ 1][t][0][0][0]);
            }
        }

        // h1(i-1) fragments (L1 A-operand; L2 x-part operand)
        half8 a0 = *(const half8*)&sH1[nxt][row8][q * 8];
        half8 a1 = *(const half8*)&sH1[nxt][row8][32 + q * 8];

        if (isL1) {
            if (i < Tt) {   // ---- L1 step i ----
                f32x4 lo = *(const f32x4*)&sXC[cbuf][t16][2 * q][row8][0];
                f32x4 hi = *(const f32x4*)&sXC[cbuf][t16][2 * q + 1][row8][0];
                union { half8 v; fp16x2 h[4]; } axu;
                axu.h[0] = __builtin_amdgcn_cvt_pkrtz(lo[0], lo[1]);
                axu.h[1] = __builtin_amdgcn_cvt_pkrtz(lo[2], lo[3]);
                axu.h[2] = __builtin_amdgcn_cvt_pkrtz(hi[0], hi[1]);
                axu.h[3] = __builtin_amdgcn_cvt_pkrtz(hi[2], hi[3]);

                f32x4 acc[4];
                #pragma unroll
                for (int G = 0; G < 4; ++G) {
                    f32x4 a = {bias[G], bias[G], bias[G], bias[G]};
                    a = MFMA16(a0, w[G][0], a);
                    a = MFMA16(a1, w[G][1], a);
                    a = MFMA16(axu.v, w[G][2], a);
                    acc[G] = a;
                }
                float h0  = lstm_unit(acc[0][r0], acc[1][r0], acc[2][r0], acc[3][r0], csA);
                float h1v = lstm_unit(acc[0][r1], acc[1][r1], acc[2][r1], acc[3][r1], csB);
                sH1[cur][bLo][colL1]     = (_Float16)h0;
                sH1[cur][bLo + 1][colL1] = (_Float16)h1v;
            }
        } else if (i >= 1) {   // ---- L2 step i-1 ----
            half8 ah = *(const half8*)&sH2[cur][row8][q * 8];
            f32x4 acc[4];
            #pragma unroll
            for (int G = 0; G < 4; ++G) {
                f32x4 a = {bias[G], bias[G], bias[G], bias[G]};
                a = MFMA16(ah, w[G][0], a);
                a = MFMA16(a0, w[G][1], a);
                a = MFMA16(a1, w[G][2], a);
                acc[G] = a;
            }
            float h2v = lstm_unit(acc[0][rL2], acc[1][rL2], acc[2][rL2], acc[3][rL2], csA);
            sH2[nxt][bL2][hL2] = (_Float16)h2v;
            if (i == Tt) sHead[bL2][hL2] = h2v;
        }

        __syncthreads();   // single barrier per step
    }

    // ---- head ----
    if (tid < BT * NTAPS) {
        int b = tid / NTAPS, n = tid - b * NTAPS;
        float s = bhead[n];
        #pragma unroll
        for (int k = 0; k < H2; ++k) s = fmaf(sHead[b][k], Whead[n * H2 + k], s);
        out[(size_t)(b0 + b) * NTAPS + n] = s;
    }
}

extern "C" void kernel_launch(void* const* d_in, const int* in_sizes, int n_in,
                              void* d_out, int out_size, void* d_ws, size_t ws_size,
                              hipStream_t stream) {
    const float* xp    = (const float*)d_in[0];
    const float* Wih1  = (const float*)d_in[1];
    const float* Whh1  = (const float*)d_in[2];
    const float* bih1  = (const float*)d_in[3];
    const float* bhh1  = (const float*)d_in[4];
    const float* Wih2  = (const float*)d_in[5];
    const float* Whh2  = (const float*)d_in[6];
    const float* bih2  = (const float*)d_in[7];
    const float* bhh2  = (const float*)d_in[8];
    const float* Whead = (const float*)d_in[9];
    const float* bhead = (const float*)d_in[10];
    float* outp = (float*)d_out;

    hipLaunchKernelGGL(lstm2_fused, dim3(Bsz / BT), dim3(NTHR), 0, stream,
                       xp, Wih1, Whh1, bih1, bhh1, Wih2, Whh2, bih2, bhh2,
                       Whead, bhead, outp);
}

// Round 2
// 392.321 us; speedup vs baseline: 1.0558x; 1.0459x over previous
//
#include <hip/hip_runtime.h>

#define Bsz 4096
#define Tt  256
#define Ff  32
#define H1  64
#define H2  32
#define NTAPS 3
#define BT  16      // 256 blocks -> 1 block/CU, full 16-row A-fragments
#define NTHR 512    // 8 waves: 0-3 L1(h-part), 4-7 L2(split)+XG precompute+DMA
#define CH  16      // x-staging chunk (timesteps)

typedef _Float16 half8  __attribute__((ext_vector_type(8)));
typedef __fp16   fp16x2 __attribute__((ext_vector_type(2)));   // cvt_pkrtz return type
typedef float    f32x4  __attribute__((ext_vector_type(4)));

#define H1S 72   // f16 row strides (16B-aligned, bank-spread)
#define H2S 40
#define HDS 33

// fused LSTM unit: 5 exp + 2 rcp (f/ig reciprocals merged, algebraically exact)
__device__ __forceinline__ float lstm_unit(float pi, float pf, float pg, float po,
                                           float& c) {
    const float K1 = 1.4426950408889634f;   // log2(e)
    float ei = __builtin_amdgcn_exp2f(-K1 * pi);
    float ef = __builtin_amdgcn_exp2f(-K1 * pf);
    float eg = __builtin_amdgcn_exp2f(-2.0f * K1 * __builtin_fabsf(pg));
    float eo = __builtin_amdgcn_exp2f(-K1 * po);
    float p1 = (1.0f + ei) * (1.0f + eg);
    float pf1 = 1.0f + ef;
    float R  = __builtin_amdgcn_rcpf(p1 * pf1);          // 1/((1+ei)(1+eg)(1+ef))
    float t1 = c * p1;                                    // c*(1+ei)(1+eg)
    float t2 = __builtin_copysignf(1.0f - eg, pg) * pf1;  // tanh(g)num*sig(i)num*(1+ef)
    c = (t1 + t2) * R;                                    // f*c + i*g
    float ec = __builtin_amdgcn_exp2f(-2.0f * K1 * __builtin_fabsf(c));
    float th = (1.0f - ec) * __builtin_amdgcn_rcpf((1.0f + eo) * (1.0f + ec));
    return __builtin_copysignf(th, c);                    // o*tanh(c)
}

#define MFMA16(a, b, c) __builtin_amdgcn_mfma_f32_16x16x32_f16((a), (b), (c), 0, 0, 0)

// async global->LDS DMA, 16B per lane; LDS dst = uniform base + lane*16
__device__ __forceinline__ void dma16(const float* gp, const float* lp) {
    __builtin_amdgcn_global_load_lds(
        (const __attribute__((address_space(1))) void*)gp,
        (__attribute__((address_space(3))) void*)lp, 16, 0, 0);
}

__device__ __forceinline__ half8 cvt8(f32x4 lo, f32x4 hi) {
    union { half8 v; fp16x2 h[4]; } ax;
    ax.h[0] = __builtin_amdgcn_cvt_pkrtz(lo[0], lo[1]);
    ax.h[1] = __builtin_amdgcn_cvt_pkrtz(lo[2], lo[3]);
    ax.h[2] = __builtin_amdgcn_cvt_pkrtz(hi[0], hi[1]);
    ax.h[3] = __builtin_amdgcn_cvt_pkrtz(hi[2], hi[3]);
    return ax.v;
}

__global__ __launch_bounds__(NTHR, 2)
void lstm2_fused(const float* __restrict__ x,
                 const float* __restrict__ Wih1, const float* __restrict__ Whh1,
                 const float* __restrict__ bih1, const float* __restrict__ bhh1,
                 const float* __restrict__ Wih2, const float* __restrict__ Whh2,
                 const float* __restrict__ bih2, const float* __restrict__ bhh2,
                 const float* __restrict__ Whead, const float* __restrict__ bhead,
                 float* __restrict__ out)
{
    __shared__ __align__(16) _Float16 sH1[2][BT][H1S];
    __shared__ __align__(16) _Float16 sH2[2][BT][H2S];
    // x chunk: [buf][t][f4][b][4] f32 — (f4-major, b-minor) so DMA lane*16B is contiguous
    __shared__ __align__(16) float    sXC[2][CH][8][BT][4];
    // precomputed x-gates: [buf][h-tile][gate][lane][4] f32 (lane-linear, conflict-free)
    __shared__ __align__(16) float    sXG[2][4][4][64][4];
    __shared__ __align__(16) float    sHead[BT][HDS];

    const int tid  = threadIdx.x;
    const int wid  = tid >> 6;        // 0..7
    const int lane = tid & 63;
    const int l15  = lane & 15;
    const int q    = lane >> 4;       // 0..3
    const int b0   = blockIdx.x * BT;
    const int u    = wid & 3;         // L1: h-tile; L2/XG: sub-role index
    const bool isL1 = (wid < 4);

    // L2 sub-role: pair (4,6) tile 0, (5,7) tile 1; rh selects acc rows 0-1 / 2-3
    const int hT = u & 1, rh = u >> 1;
    const int colL1 = u * 16 + l15;

    // DMA lane mapping: lane = f4*16 + b within a half-t load
    const int bL  = lane & 15;
    const int f4b = lane >> 4;        // 0..3
    const float* gbase = x + (size_t)(b0 + bL) * Tt * Ff;

    // ---- prologue: waves 4-7 kick chunk 0 DMA immediately ----
    if (!isL1) {
        #pragma unroll
        for (int j = 0; j < 4; ++j) {
            int tl = u * 4 + j;
            #pragma unroll
            for (int h = 0; h < 2; ++h)
                dma16(gbase + (size_t)tl * Ff + (h * 4 + f4b) * 4,
                      &sXC[0][tl][h * 4][0][0]);
        }
    }

    // ---- weight fragments (registers, one time) ----
    half8 wA[4][3];     // L1: [G][c] c=0,1 h1-part; L2: c=0 h2, c=1,2 h1
    half8 wX[4];        // XG: x->gate frags (waves 4-7 only)
    float biasA[4], biasX[4];
    if (isL1) {
        #pragma unroll
        for (int G = 0; G < 4; ++G) {
            int gr = G * 64 + colL1;               // L1 gate row
            #pragma unroll
            for (int c = 0; c < 2; ++c) {
                half8 v;
                #pragma unroll
                for (int e = 0; e < 8; ++e)
                    v[e] = (_Float16)Whh1[gr * H1 + c * 32 + q * 8 + e];
                wA[G][c] = v;
            }
            wA[G][2] = wA[G][1];   // unused
            biasA[G] = 0.0f;       // bias folded into xg
            biasX[G] = 0.0f;
        }
    } else {
        #pragma unroll
        for (int G = 0; G < 4; ++G) {
            int gr2 = G * 32 + hT * 16 + l15;      // L2 gate row
            half8 v0, v1, v2, vx;
            #pragma unroll
            for (int e = 0; e < 8; ++e) {
                int k = q * 8 + e;
                v0[e] = (_Float16)Whh2[gr2 * H2 + k];
                v1[e] = (_Float16)Wih2[gr2 * H1 + k];
                v2[e] = (_Float16)Wih2[gr2 * H1 + 32 + k];
            }
            wA[G][0] = v0; wA[G][1] = v1; wA[G][2] = v2;
            biasA[G] = bih2[gr2] + bhh2[gr2];

            int grx = G * 64 + u * 16 + l15;       // XG gate row (tile u)
            #pragma unroll
            for (int e = 0; e < 8; ++e)
                vx[e] = (_Float16)Wih1[grx * Ff + q * 8 + e];
            wX[G] = vx;
            biasX[G] = bih1[grx] + bhh1[grx];
        }
    }

    // ---- zero h(-1) buffers ----
    for (int idx = tid; idx < BT * H1S; idx += NTHR) ((_Float16*)sH1[1])[idx] = (_Float16)0.0f;
    for (int idx = tid; idx < BT * H2S; idx += NTHR) ((_Float16*)sH2[1])[idx] = (_Float16)0.0f;

    __syncthreads();   // drains chunk-0 DMA + init writes

    // ---- XG prologue: xg(0) into sXG[0] ----
    if (!isL1) {
        f32x4 lo = *(const f32x4*)&sXC[0][0][2 * q][l15][0];
        f32x4 hi = *(const f32x4*)&sXC[0][0][2 * q + 1][l15][0];
        half8 ax = cvt8(lo, hi);
        #pragma unroll
        for (int G = 0; G < 4; ++G) {
            f32x4 a = {biasX[G], biasX[G], biasX[G], biasX[G]};
            a = MFMA16(ax, wX[G], a);
            *(f32x4*)&sXG[0][u][G][lane][0] = a;
        }
    }
    __syncthreads();

    float cs0 = 0.0f, cs1 = 0.0f, cs2 = 0.0f, cs3 = 0.0f;

    #pragma unroll 2
    for (int i = 0; i < Tt; ++i) {
        const int cur = i & 1, nxt = cur ^ 1;
        const int cbuf = (i >> 4) & 1;

        // ---- chunk-boundary DMA at TOP of step (latency hides under compute) ----
        if (!isL1 && (i & (CH - 1)) == 0 && i + CH < Tt) {
            const float* gb = gbase + (size_t)(i + CH) * Ff;
            #pragma unroll
            for (int j = 0; j < 4; ++j) {
                int tl = u * 4 + j;
                #pragma unroll
                for (int h = 0; h < 2; ++h)
                    dma16(gb + (size_t)tl * Ff + (h * 4 + f4b) * 4,
                          &sXC[cbuf ^ 1][tl][h * 4][0][0]);
            }
        }

        // h1(i-1) fragments (L1 A-operand; L2 K-part operand)
        half8 a0 = *(const half8*)&sH1[nxt][l15][q * 8];
        half8 a1 = *(const half8*)&sH1[nxt][l15][32 + q * 8];

        if (isL1) {   // ---- L1 step i: C-init from precomputed xg, 8 MFMAs ----
            f32x4 acc[4];
            #pragma unroll
            for (int G = 0; G < 4; ++G) {
                f32x4 a = *(const f32x4*)&sXG[cur][u][G][lane][0];
                a = MFMA16(a0, wA[G][0], a);
                a = MFMA16(a1, wA[G][1], a);
                acc[G] = a;
            }
            float h0 = lstm_unit(acc[0][0], acc[1][0], acc[2][0], acc[3][0], cs0);
            float h1v = lstm_unit(acc[0][1], acc[1][1], acc[2][1], acc[3][1], cs1);
            float h2v = lstm_unit(acc[0][2], acc[1][2], acc[2][2], acc[3][2], cs2);
            float h3v = lstm_unit(acc[0][3], acc[1][3], acc[2][3], acc[3][3], cs3);
            sH1[cur][q * 4 + 0][colL1] = (_Float16)h0;
            sH1[cur][q * 4 + 1][colL1] = (_Float16)h1v;
            sH1[cur][q * 4 + 2][colL1] = (_Float16)h2v;
            sH1[cur][q * 4 + 3][colL1] = (_Float16)h3v;
        } else {
            if (i >= 1) {   // ---- L2 step i-1 (MFMAs duplicated per pair; lstm split) ----
                half8 ah = *(const half8*)&sH2[cur][l15][q * 8];
                f32x4 acc[4];
                #pragma unroll
                for (int G = 0; G < 4; ++G) {
                    f32x4 a = {biasA[G], biasA[G], biasA[G], biasA[G]};
                    a = MFMA16(ah, wA[G][0], a);
                    a = MFMA16(a0, wA[G][1], a);
                    a = MFMA16(a1, wA[G][2], a);
                    acc[G] = a;
                }
                int r = rh * 2;
                float hA = lstm_unit(acc[0][r],     acc[1][r],     acc[2][r],     acc[3][r],     cs0);
                float hB = lstm_unit(acc[0][r + 1], acc[1][r + 1], acc[2][r + 1], acc[3][r + 1], cs1);
                sH2[nxt][q * 4 + r][hT * 16 + l15]     = (_Float16)hA;
                sH2[nxt][q * 4 + r + 1][hT * 16 + l15] = (_Float16)hB;
            }
            if (i + 1 < Tt) {   // ---- XG: xg(i+1) into sXG[nxt] ----
                const int t = i + 1, cb = (t >> 4) & 1, t16 = t & (CH - 1);
                f32x4 lo = *(const f32x4*)&sXC[cb][t16][2 * q][l15][0];
                f32x4 hi = *(const f32x4*)&sXC[cb][t16][2 * q + 1][l15][0];
                half8 ax = cvt8(lo, hi);
                #pragma unroll
                for (int G = 0; G < 4; ++G) {
                    f32x4 a = {biasX[G], biasX[G], biasX[G], biasX[G]};
                    a = MFMA16(ax, wX[G], a);
                    *(f32x4*)&sXG[nxt][u][G][lane][0] = a;
                }
            }
        }

        __syncthreads();   // single barrier per step
    }

    // ---- epilogue: step Tt (final L2 step, t = Tt-1) -> sHead ----
    {
        const int cur = Tt & 1;        // 0
        const int nxt = cur ^ 1;       // 1
        if (!isL1) {
            half8 a0 = *(const half8*)&sH1[nxt][l15][q * 8];
            half8 a1 = *(const half8*)&sH1[nxt][l15][32 + q * 8];
            half8 ah = *(const half8*)&sH2[cur][l15][q * 8];
            f32x4 acc[4];
            #pragma unroll
            for (int G = 0; G < 4; ++G) {
                f32x4 a = {biasA[G], biasA[G], biasA[G], biasA[G]};
                a = MFMA16(ah, wA[G][0], a);
                a = MFMA16(a0, wA[G][1], a);
                a = MFMA16(a1, wA[G][2], a);
                acc[G] = a;
            }
            int r = rh * 2;
            float hA = lstm_unit(acc[0][r],     acc[1][r],     acc[2][r],     acc[3][r],     cs0);
            float hB = lstm_unit(acc[0][r + 1], acc[1][r + 1], acc[2][r + 1], acc[3][r + 1], cs1);
            sHead[q * 4 + r][hT * 16 + l15]     = hA;
            sHead[q * 4 + r + 1][hT * 16 + l15] = hB;
        }
        __syncthreads();
    }

    // ---- head ----
    if (tid < BT * NTAPS) {
        int b = tid / NTAPS, n = tid - b * NTAPS;
        float s = bhead[n];
        #pragma unroll
        for (int k = 0; k < H2; ++k) s = fmaf(sHead[b][k], Whead[n * H2 + k], s);
        out[(size_t)(b0 + b) * NTAPS + n] = s;
    }
}

extern "C" void kernel_launch(void* const* d_in, const int* in_sizes, int n_in,
                              void* d_out, int out_size, void* d_ws, size_t ws_size,
                              hipStream_t stream) {
    const float* xp    = (const float*)d_in[0];
    const float* Wih1  = (const float*)d_in[1];
    const float* Whh1  = (const float*)d_in[2];
    const float* bih1  = (const float*)d_in[3];
    const float* bhh1  = (const float*)d_in[4];
    const float* Wih2  = (const float*)d_in[5];
    const float* Whh2  = (const float*)d_in[6];
    const float* bih2  = (const float*)d_in[7];
    const float* bhh2  = (const float*)d_in[8];
    const float* Whead = (const float*)d_in[9];
    const float* bhead = (const float*)d_in[10];
    float* outp = (float*)d_out;

    hipLaunchKernelGGL(lstm2_fused, dim3(Bsz / BT), dim3(NTHR), 0, stream,
                       xp, Wih1, Whh1, bih1, bhh1, Wih2, Whh2, bih2, bhh2,
                       Whead, bhead, outp);
}